// Round 20
// baseline (725.663 us; speedup 1.0000x reference)
//
#include <hip/hip_runtime.h>
#include <cfloat>
#include <cmath>
#include <climits>
#include <cstdint>

// Problem constants
#define N_ROWS   32768
#define D_DIM    512
#define K_CODES  4096

#define EPS_GAP  0.008f     // MFMA-path gap below which we re-check via np-emulation
#define CAND_WIN 0.02f      // fp32-screen window that provably contains the np-argmin
#define FLAG_CAP 12000

typedef short s16x8 __attribute__((ext_vector_type(8)));
typedef float f32x4 __attribute__((ext_vector_type(4)));

// ---------------------------------------------------------------------------
// Flat scratch layout in d_out (float indices). Sizes derived as
// (#shorts * 2 bytes) / 4 = floats, written out explicitly:
//  out_q zone [0,16777216):
//    lat_lo  16,777,216 shorts = 33,554,432 B = 8,388,608 f  [0, 8388608)
//    emb_hi   2,097,152 shorts =  4,194,304 B = 1,048,576 f  [8388608, 9437184)
//    emb_lo   2,097,152 shorts =  4,194,304 B = 1,048,576 f  [9437184, 10485760)
//    pmin    2x32768 f                                        [10485760, 10551296)
//    pidxgap 65,536 u32 = 65,536 f                            [10551296, 10616832)
//    e_norm  4,096 f                                          [10616832, 10620928)
//    (all consumed by vq_argmin/vq_select, which run BEFORE vq_gather
//     overwrites out_q)
//  out_emb zone [16809985,18907137):
//    flagcnt 1                                                [16810000]
//    flaglist 12,000                                          [16810001, 16822001)
//    fidx    32,768 u16 = 65,536 B = 16,384 f                 [16822016, 16838400)
//    hist    4,096 ints = 16,384 B = 4,096 f                  [16838400, 16842496)
//    rowpart 32,768 f                                         [16842496, 16875264)
//    (disjoint; all dead before the final emb memcpy)
// Outputs: out_q[0,16777216) loss[16777216] inds[16777217,16809985)
//          emb[16809985,18907137) perp[18907137]
// ---------------------------------------------------------------------------

__device__ __forceinline__ short f2bf_rne(float x) {
    unsigned u = __float_as_uint(x);
    unsigned r = (u + 0x7fffu + ((u >> 16) & 1u)) >> 16;
    return (short)r;
}
__device__ __forceinline__ float bf2f(short b) {
    return __uint_as_float(((unsigned)(unsigned short)b) << 16);
}

// truncation split: hi = top 16 bits of x; r = x - bf2f(hi) exact (Sterbenz);
// lo = top 16 bits of r.  (identical to rounds 18/19)
__device__ __forceinline__ void trunc_split8(const float* x, s16x8* hv, s16x8* lv) {
    #pragma unroll
    for (int j = 0; j < 8; ++j) {
        unsigned ux = __float_as_uint(x[j]);
        short h = (short)(ux >> 16);
        (*hv)[j] = h;
        float r = x[j] - bf2f(h);
        (*lv)[j] = (short)(__float_as_uint(r) >> 16);
    }
}
__device__ __forceinline__ s16x8 hi8(const float* x) {
    s16x8 hv;
    #pragma unroll
    for (int j = 0; j < 8; ++j)
        hv[j] = (short)(__float_as_uint(x[j]) >> 16);
    return hv;
}

__device__ __forceinline__ void gld16(const short* g, short* l) {
    __builtin_amdgcn_global_load_lds(
        reinterpret_cast<const __attribute__((address_space(1))) unsigned int*>(
            reinterpret_cast<uintptr_t>(g)),
        reinterpret_cast<__attribute__((address_space(3))) unsigned int*>(
            (unsigned int)(reinterpret_cast<uintptr_t>(l))),
        16, 0, 0);
}

// ---------------------------------------------------------------------------
// numpy fp32 pairwise-sum emulation (AVX512/GCC path) -- unchanged, proven.
// ---------------------------------------------------------------------------
__device__ __forceinline__ float np_block128_sq(const float* p) {
    float P[16];
    #pragma unroll
    for (int l = 0; l < 16; ++l) {
        float s0 = __fmul_rn(p[0 * 16 + l], p[0 * 16 + l]);
        float s1 = __fmul_rn(p[1 * 16 + l], p[1 * 16 + l]);
        float s2 = __fmul_rn(p[2 * 16 + l], p[2 * 16 + l]);
        float s3 = __fmul_rn(p[3 * 16 + l], p[3 * 16 + l]);
        float s4 = __fmul_rn(p[4 * 16 + l], p[4 * 16 + l]);
        float s5 = __fmul_rn(p[5 * 16 + l], p[5 * 16 + l]);
        float s6 = __fmul_rn(p[6 * 16 + l], p[6 * 16 + l]);
        float s7 = __fmul_rn(p[7 * 16 + l], p[7 * 16 + l]);
        float a01 = __fadd_rn(s0, s1);
        float a23 = __fadd_rn(s2, s3);
        float a45 = __fadd_rn(s4, s5);
        float a67 = __fadd_rn(s6, s7);
        P[l] = __fadd_rn(__fadd_rn(a01, a23), __fadd_rn(a45, a67));
    }
    float T3[8];
    #pragma unroll
    for (int k = 0; k < 8; ++k) T3[k] = __fadd_rn(P[k], P[k + 8]);
    float T6[4];
    #pragma unroll
    for (int k = 0; k < 4; ++k) T6[k] = __fadd_rn(T3[k], T3[k + 4]);
    return __fadd_rn(__fadd_rn(__fadd_rn(T6[0], T6[1]), T6[2]), T6[3]);
}
__device__ __forceinline__ float np_sum512_sq(const float* p) {
    float B0 = np_block128_sq(p);
    float B1 = np_block128_sq(p + 128);
    float B2 = np_block128_sq(p + 256);
    float B3 = np_block128_sq(p + 384);
    return __fadd_rn(__fadd_rn(B0, B1), __fadd_rn(B2, B3));
}

// ---------------------------------------------------------------------------
// Kernel 0: precompute lat_lo (trunc split, lo only) + emb RNE hi/lo + e_norm.
// Blocks 0..8191: lat octets.  Blocks 8192..9215: emb (wave = 1 row).
// ---------------------------------------------------------------------------
__global__ void vq_conv(const float* __restrict__ lat, const float* __restrict__ emb,
                        short* __restrict__ lat_lo,
                        short* __restrict__ emb_hi, short* __restrict__ emb_lo,
                        float* __restrict__ e_norm) {
    int i = blockIdx.x * 256 + threadIdx.x;   // octet index
    if (i < 2097152) {                        // lat: 2,097,152 octets
        size_t base = (size_t)i * 8;
        float4 a = *(const float4*)(lat + base);
        float4 b = *(const float4*)(lat + base + 4);
        float x[8] = {a.x, a.y, a.z, a.w, b.x, b.y, b.z, b.w};
        s16x8 hv, lv;
        trunc_split8(x, &hv, &lv);
        *(s16x8*)(lat_lo + base) = lv;        // hi recomputed in-kernel (1 shift)
    } else {                                  // emb: 262,144 octets
        int j = i - 2097152;
        int lane = threadIdx.x & 63;
        size_t base = (size_t)j * 8;
        float4 a = *(const float4*)(emb + base);
        float4 b = *(const float4*)(emb + base + 4);
        float x[8] = {a.x, a.y, a.z, a.w, b.x, b.y, b.z, b.w};
        s16x8 hv, lv;
        float s = 0.f;
        #pragma unroll
        for (int q = 0; q < 8; ++q) {
            short h = f2bf_rne(x[q]);
            hv[q] = h;
            lv[q] = f2bf_rne(x[q] - bf2f(h));
            s = __fmaf_rn(x[q], x[q], s);
        }
        *(s16x8*)(emb_hi + base) = hv;
        *(s16x8*)(emb_lo + base) = lv;
        #pragma unroll
        for (int off = 32; off > 0; off >>= 1) s += __shfl_xor(s, off);
        if (lane == 0) e_norm[j >> 6] = s;    // 64 octets per emb row
    }
}

// ---------------------------------------------------------------------------
// Kernel 2: MFMA split-bf16 distance GEMM. Block = 256 rows x 256 codes,
// grid (128, 2 K-halves). 16 waves (4x4), wave tile 64x64. A: f32 loads ->
// hi via 1 shift/elem + ds_write; lo via gld16 from precomputed lat_lo.
// B: gld16 from RNE-split emb. Distances bit-identical to round 18 (passed).
// ---------------------------------------------------------------------------
__device__ __forceinline__ int kswz(int r) { return (r & 3) ^ ((r >> 2) & 3); }

#define BROWS 256
#define KHALF 2048
#define BUFS2 32768   // shorts/buffer: Ah 8192 | Al 8192 | Bh 8192 | Bl 8192

__global__ __launch_bounds__(1024, 4)
void vq_argmin_mfma(const float* __restrict__ lat, const short* __restrict__ Al_g,
                    const short* __restrict__ Bh_g, const short* __restrict__ Bl_g,
                    const float* __restrict__ e_norm,
                    float* __restrict__ pmin, unsigned* __restrict__ pidxgap)
{
    __shared__ short smem[2 * BUFS2];     // 128KB
    __shared__ float pbest_s[4][256];     // [wc][row]
    __shared__ float psec_s[4][256];
    __shared__ int   pidx_s[4][256];

    const int tid = threadIdx.x;
    const int l   = tid & 63;
    const int wid = tid >> 6;      // 0..15
    const int wr  = wid >> 2;      // 0..3 -> rows wr*64..+63
    const int wc  = wid & 3;       // 0..3 -> cols wc*64..+63
    const int l15 = l & 15;
    const int lhi = l >> 4;
    const int row0  = blockIdx.x * BROWS;
    const int kbase = blockIdx.y * KHALF;

    // init persistent reduce state (1024 entries each)
    ((float*)pbest_s)[tid] = FLT_MAX;
    ((float*)psec_s)[tid]  = FLT_MAX;
    ((int*)pidx_s)[tid]    = 0;

    int offA[4], offB[4];
    #pragma unroll
    for (int m = 0; m < 4; ++m) {
        int r = wr * 64 + m * 16 + l15;
        offA[m] = r * 32 + (lhi ^ kswz(r)) * 8;
    }
    #pragma unroll
    for (int n = 0; n < 4; ++n) {
        int c = wc * 64 + n * 16 + l15;
        offB[n] = c * 32 + (lhi ^ kswz(c)) * 8;
    }

    // staging constants: thread t -> row t>>2, slot t&3, source chunk slot^kswz(row)
    const int rr = tid >> 2, sl = tid & 3;
    const int chk = sl ^ kswz(rr);
    const size_t a_off = (size_t)(row0 + rr) * D_DIM + chk * 8;  // elem offset
    const int dst = tid * 8;

    // prologue: stage step 0 into buf 0
    {
        gld16(Al_g + a_off, smem + 8192 + dst);
        size_t go = (size_t)(kbase + rr) * D_DIM + chk * 8;
        gld16(Bh_g + go, smem + 16384 + dst);
        gld16(Bl_g + go, smem + 24576 + dst);
        const float* p = lat + a_off;
        float4 f0 = *(const float4*)p;
        float4 f1 = *(const float4*)(p + 4);
        float x[8] = {f0.x, f0.y, f0.z, f0.w, f1.x, f1.y, f1.z, f1.w};
        s16x8 hv = hi8(x);
        *(s16x8*)(smem + dst) = hv;
    }
    __syncthreads();

    f32x4 acc[4][4];
    #pragma unroll
    for (int m = 0; m < 4; ++m)
        #pragma unroll
        for (int n = 0; n < 4; ++n) acc[m][n] = (f32x4){0.f, 0.f, 0.f, 0.f};

    for (int s = 0; s < 128; ++s) {
        short* cur = smem + (s & 1) * BUFS2;
        short* nxt = smem + ((s & 1) ^ 1) * BUFS2;

        float4 nf0, nf1;
        if (s < 127) {
            const int s1 = s + 1;
            const int k0 = (s1 & 15) * 32;
            gld16(Al_g + a_off + k0, nxt + 8192 + dst);
            size_t go = (size_t)(kbase + (s1 >> 4) * 256 + rr) * D_DIM + k0 + chk * 8;
            gld16(Bh_g + go, nxt + 16384 + dst);
            gld16(Bl_g + go, nxt + 24576 + dst);
            const float* p = lat + a_off + k0;
            nf0 = *(const float4*)p;
            nf1 = *(const float4*)(p + 4);
        }

        s16x8 ah[4], al[4];
        #pragma unroll
        for (int m = 0; m < 4; ++m) {
            ah[m] = *(const s16x8*)(cur + offA[m]);
            al[m] = *(const s16x8*)(cur + 8192 + offA[m]);
        }
        __builtin_amdgcn_s_setprio(1);
        #pragma unroll
        for (int n = 0; n < 4; ++n) {
            s16x8 bh = *(const s16x8*)(cur + 16384 + offB[n]);
            s16x8 bl = *(const s16x8*)(cur + 24576 + offB[n]);
            #pragma unroll
            for (int m = 0; m < 4; ++m) {
                acc[m][n] = __builtin_amdgcn_mfma_f32_16x16x32_bf16(ah[m], bh, acc[m][n], 0, 0, 0);
                acc[m][n] = __builtin_amdgcn_mfma_f32_16x16x32_bf16(ah[m], bl, acc[m][n], 0, 0, 0);
                acc[m][n] = __builtin_amdgcn_mfma_f32_16x16x32_bf16(al[m], bh, acc[m][n], 0, 0, 0);
            }
        }
        __builtin_amdgcn_s_setprio(0);

        if ((s & 15) == 15) {
            // per-code-tile epilogue: fold into persistent LDS state
            const int cb0 = kbase + (s >> 4) * 256;
            float en[4];
            int   cc[4];
            #pragma unroll
            for (int n = 0; n < 4; ++n) {
                cc[n] = cb0 + wc * 64 + n * 16 + l15;
                en[n] = e_norm[cc[n]];
            }
            #pragma unroll
            for (int m = 0; m < 4; ++m)
                #pragma unroll
                for (int r = 0; r < 4; ++r) {
                    float v = FLT_MAX, sc = FLT_MAX;
                    int ii = 0;
                    #pragma unroll
                    for (int n = 0; n < 4; ++n) {
                        float dv = __fmaf_rn(-2.f, acc[m][n][r], en[n]);
                        if (dv < v) { sc = v; v = dv; ii = cc[n]; }
                        else if (dv < sc) sc = dv;
                    }
                    // reduce over the 16 l15 lanes (columns)
                    #pragma unroll
                    for (int off = 8; off > 0; off >>= 1) {
                        float v2 = __shfl_xor(v, off);
                        float s2 = __shfl_xor(sc, off);
                        int   i2 = __shfl_xor(ii, off);
                        float ns = fminf(fminf(sc, s2), fmaxf(v, v2));
                        if (v2 < v || (v2 == v && i2 < ii)) { v = v2; ii = i2; }
                        sc = ns;
                    }
                    if (l15 == 0) {
                        int rb = wr * 64 + m * 16 + lhi * 4 + r;
                        float ob = pbest_s[wc][rb];
                        float os = psec_s[wc][rb];
                        float nsec = fminf(fminf(os, sc), fmaxf(ob, v));
                        if (v < ob) { pbest_s[wc][rb] = v; pidx_s[wc][rb] = ii; }
                        psec_s[wc][rb] = nsec;
                    }
                }
            #pragma unroll
            for (int m = 0; m < 4; ++m)
                #pragma unroll
                for (int n = 0; n < 4; ++n) acc[m][n] = (f32x4){0.f, 0.f, 0.f, 0.f};
        }

        if (s < 127) {
            // hi extraction (1 shift/elem) + swizzled ds_write of next A-hi
            float x[8] = {nf0.x, nf0.y, nf0.z, nf0.w, nf1.x, nf1.y, nf1.z, nf1.w};
            s16x8 hv = hi8(x);
            *(s16x8*)(nxt + dst) = hv;
        }
        __syncthreads();   // drains gld16 (vmcnt) + ds_write (lgkm)
    }

    // final merge over the 4 wc waves; write pmin + packed (idx<<16 | gap*4096)
    if (tid < 256) {
        float B = FLT_MAX, S = FLT_MAX;
        int I = 0;
        #pragma unroll
        for (int w = 0; w < 4; ++w) {
            float b = pbest_s[w][tid], s = psec_s[w][tid];
            int i = pidx_s[w][tid];
            if (b < B || (b == B && i < I)) { S = fminf(B, s); B = b; I = i; }
            else S = fminf(S, fminf(b, s));
        }
        int row = row0 + tid;
        pmin[blockIdx.y * N_ROWS + row] = B;
        float gap = S - B;                    // >= 0, finite
        unsigned g16 = (unsigned)fminf(gap * 4096.f, 65535.f);  // trunc -> flag superset
        pidxgap[blockIdx.y * N_ROWS + row] = ((unsigned)I << 16) | g16;
    }
}

// ---------------------------------------------------------------------------
// Kernel 2b: EXACT merge of the two K-halves -> fidx + out_inds + flag list.
// sec_h reconstructed as best_h + gap_h (gap truncated => conservative flag).
// ---------------------------------------------------------------------------
__global__ void vq_select(const float* __restrict__ pmin,
                          const unsigned* __restrict__ pidxgap,
                          unsigned short* __restrict__ fidx, float* __restrict__ out_inds,
                          int* __restrict__ flagcnt, int* __restrict__ flaglist) {
    int row = blockIdx.x * 256 + threadIdx.x;
    float v0 = pmin[row], v1 = pmin[N_ROWS + row];
    unsigned p0 = pidxgap[row], p1 = pidxgap[N_ROWS + row];
    float s0 = v0 + (float)(p0 & 0xFFFFu) * (1.f / 4096.f);
    float s1 = v1 + (float)(p1 & 0xFFFFu) * (1.f / 4096.f);
    int i0 = (int)(p0 >> 16), i1 = (int)(p1 >> 16);

    float best, sec; int bi;
    if (v1 < v0) { best = v1; bi = i1; sec = fminf(s1, v0); }
    else         { best = v0; bi = i0; sec = fminf(s0, v1); }  // tie -> half 0

    fidx[row] = (unsigned short)bi;
    out_inds[row] = (float)bi;
    if (sec - best < EPS_GAP) {
        int p = atomicAdd(flagcnt, 1);
        if (p < FLAG_CAP) flaglist[p] = row;
    }
}

// ---------------------------------------------------------------------------
// Kernel 3: flagged-row resolve — one row per block, 16 waves, x2 unroll,
// fp32 screen + bit-exact np eval. Also writes out_inds for its rows.
// ---------------------------------------------------------------------------
#define FIXT 1024
#define NWAV 16
#define MAXC 128

__global__ __launch_bounds__(FIXT)
void vq_fixrow(const float* __restrict__ lat, const float* __restrict__ emb,
               const int* __restrict__ flagcnt, const int* __restrict__ flaglist,
               unsigned short* __restrict__ fidx, float* __restrict__ out_inds)
{
    __shared__ float xs[D_DIM];
    __shared__ float dall[K_CODES];
    __shared__ float wmin_s[NWAV];
    __shared__ int   ccnt;
    __shared__ int   cands[MAXC];
    __shared__ float cd32[MAXC];

    const int t    = threadIdx.x;
    const int wave = t >> 6;
    const int lane = t & 63;
    int cnt = *flagcnt;
    if (cnt > FLAG_CAP) cnt = FLAG_CAP;

    for (int f = blockIdx.x; f < cnt; f += gridDim.x) {
        const int row = flaglist[f];
        __syncthreads();
        if (t < D_DIM) xs[t] = lat[(size_t)row * D_DIM + t];
        if (t == 0) ccnt = 0;
        __syncthreads();

        float x8[8];
        #pragma unroll
        for (int q = 0; q < 8; ++q) x8[q] = xs[lane * 8 + q];

        float lmin = FLT_MAX;
        for (int c = wave; c < K_CODES; c += 2 * NWAV) {
            const int c2 = c + NWAV;
            const float4* e4a = (const float4*)(emb + (size_t)c  * D_DIM);
            const float4* e4b = (const float4*)(emb + (size_t)c2 * D_DIM);
            float4 ea0 = e4a[lane * 2], ea1 = e4a[lane * 2 + 1];
            float4 eb0 = e4b[lane * 2], eb1 = e4b[lane * 2 + 1];

            float p0 = x8[0] - ea0.x, p1 = x8[1] - ea0.y;
            float p2 = x8[2] - ea0.z, p3 = x8[3] - ea0.w;
            float p4 = x8[4] - ea1.x, p5 = x8[5] - ea1.y;
            float p6 = x8[6] - ea1.z, p7 = x8[7] - ea1.w;
            float sA = __fmaf_rn(p0, p0, __fmaf_rn(p1, p1, __fmaf_rn(p2, p2, p3 * p3)));
            float sB = __fmaf_rn(p4, p4, __fmaf_rn(p5, p5, __fmaf_rn(p6, p6, p7 * p7)));
            float u = sA + sB;

            float q0 = x8[0] - eb0.x, q1 = x8[1] - eb0.y;
            float q2 = x8[2] - eb0.z, q3 = x8[3] - eb0.w;
            float q4 = x8[4] - eb1.x, q5 = x8[5] - eb1.y;
            float q6 = x8[6] - eb1.z, q7 = x8[7] - eb1.w;
            float tA = __fmaf_rn(q0, q0, __fmaf_rn(q1, q1, __fmaf_rn(q2, q2, q3 * q3)));
            float tB = __fmaf_rn(q4, q4, __fmaf_rn(q5, q5, __fmaf_rn(q6, q6, q7 * q7)));
            float v = tA + tB;

            #pragma unroll
            for (int off = 32; off > 0; off >>= 1) {
                u += __shfl_xor(u, off);
                v += __shfl_xor(v, off);
            }
            if (lane == 0) { dall[c] = u; dall[c2] = v; }
            lmin = fminf(lmin, fminf(u, v));
        }
        if (lane == 0) wmin_s[wave] = lmin;
        __syncthreads();

        float gmin = wmin_s[0];
        #pragma unroll
        for (int w = 1; w < NWAV; ++w) gmin = fminf(gmin, wmin_s[w]);
        const float thr = gmin + CAND_WIN;

        for (int c = t; c < K_CODES; c += FIXT) {
            if (dall[c] < thr) {
                int p = atomicAdd(&ccnt, 1);
                if (p < MAXC) cands[p] = c;
            }
        }
        __syncthreads();

        int nc = ccnt < MAXC ? ccnt : MAXC;
        if (t < nc) {
            int c = cands[t];
            const float* e = emb + (size_t)c * D_DIM;
            float t1 = np_sum512_sq(xs);
            float t2 = np_sum512_sq(e);
            float dot = 0.f;
            for (int k = 0; k < D_DIM; ++k)
                dot = __fmaf_rn(xs[k], e[k], dot);     // sequential, BLAS order
            cd32[t] = __fsub_rn(__fadd_rn(t1, t2), __fmul_rn(2.f, dot));
        }
        __syncthreads();

        if (t == 0) {
            float bv = cd32[0]; int bx = cands[0];
            for (int w = 1; w < nc; ++w)
                if (cd32[w] < bv || (cd32[w] == bv && cands[w] < bx)) {
                    bv = cd32[w]; bx = cands[w];
                }
            fidx[row] = (unsigned short)bx;
            out_inds[row] = (float)bx;
        }
    }
}

// ---------------------------------------------------------------------------
// Kernel 4: gather quantized rows, per-row MSE partial, histogram.
// ---------------------------------------------------------------------------
__global__ void vq_gather(const float* __restrict__ lat, const float* __restrict__ emb,
                          const unsigned short* __restrict__ fidx,
                          float* __restrict__ out_q,
                          float* __restrict__ rowpart, int* __restrict__ hist) {
    int row  = blockIdx.x * 4 + (threadIdx.x >> 6);
    int lane = threadIdx.x & 63;
    int idx  = fidx[row];

    if (lane == 0) atomicAdd(&hist[idx], 1);

    const float4* e4 = (const float4*)(emb + (size_t)idx * D_DIM);
    const float4* x4 = (const float4*)(lat + (size_t)row * D_DIM);
    float4*       q4 = (float4*)(out_q + (size_t)row * D_DIM);

    float s = 0.f;
    #pragma unroll
    for (int i = 0; i < 2; ++i) {
        float4 e = e4[i * 64 + lane];
        float4 x = x4[i * 64 + lane];
        q4[i * 64 + lane] = e;
        float dx = e.x - x.x, dy = e.y - x.y, dz = e.z - x.z, dw = e.w - x.w;
        s += dx * dx + dy * dy + dz * dz + dw * dw;
    }
    #pragma unroll
    for (int off = 32; off > 0; off >>= 1) s += __shfl_down(s, off);
    if (lane == 0) rowpart[row] = s;
}

// ---------------------------------------------------------------------------
// Kernel 5: final reductions (loss, perplexity).
// ---------------------------------------------------------------------------
__global__ void vq_finalize(const float* __restrict__ rowpart, const int* __restrict__ hist,
                            float* __restrict__ out_loss, float* __restrict__ out_perp) {
    __shared__ float sdata[256];
    int t = threadIdx.x;

    float s = 0.f;
    for (int i = t; i < N_ROWS; i += 256) s += rowpart[i];
    sdata[t] = s;
    __syncthreads();
    for (int st = 128; st > 0; st >>= 1) {
        if (t < st) sdata[t] += sdata[t + st];
        __syncthreads();
    }
    if (t == 0) out_loss[0] = 1.05f * (sdata[0] / ((float)N_ROWS * (float)D_DIM));
    __syncthreads();

    float p = 0.f;
    for (int i = t; i < K_CODES; i += 256) {
        float pr = (float)hist[i] / (float)N_ROWS;
        p += pr * logf(pr + 1e-10f);
    }
    sdata[t] = p;
    __syncthreads();
    for (int st = 128; st > 0; st >>= 1) {
        if (t < st) sdata[t] += sdata[t + st];
        __syncthreads();
    }
    if (t == 0) out_perp[0] = expf(-sdata[0]);
}

// ---------------------------------------------------------------------------
extern "C" void kernel_launch(void* const* d_in, const int* in_sizes, int n_in,
                              void* d_out, int out_size, void* d_ws, size_t ws_size,
                              hipStream_t stream) {
    const float* lat = (const float*)d_in[0];
    const float* emb = (const float*)d_in[1];
    float* ob = (float*)d_out;

    // out_q zone scratch (dead before vq_gather writes out_q)
    short* lat_lo = (short*)(ob + 0);           // [0, 8388608) floats
    short* emb_hi = (short*)(ob + 8388608);     // [8388608, 9437184)
    short* emb_lo = (short*)(ob + 9437184);     // [9437184, 10485760)
    float* pmin   = ob + 10485760;              // [10485760, 10551296)
    unsigned* pidxgap = (unsigned*)(ob + 10551296);  // [10551296, 10616832)
    float* e_norm = ob + 10616832;              // [10616832, 10620928)
    // out_emb zone scratch (dead before the final emb memcpy)
    int*   flagcnt  = (int*)(ob + 16810000);
    int*   flaglist = (int*)(ob + 16810001);    // [16810001, 16822001)
    unsigned short* fidx = (unsigned short*)(ob + 16822016);  // [16822016, 16838400)
    int*   hist    = (int*)(ob + 16838400);     // [16838400, 16842496)
    float* rowpart = ob + 16842496;             // [16842496, 16875264)

    float* out_q    = ob;
    float* out_loss = ob + 16777216;
    float* out_inds = ob + 16777217;
    float* out_emb  = ob + 16809985;
    float* out_perp = ob + 18907137;

    hipMemsetAsync(flagcnt, 0, sizeof(int), stream);
    hipMemsetAsync(hist, 0, K_CODES * sizeof(int), stream);

    vq_conv<<<dim3(9216), dim3(256), 0, stream>>>(lat, emb, lat_lo,
                                                  emb_hi, emb_lo, e_norm);

    vq_argmin_mfma<<<dim3(N_ROWS / BROWS, 2), dim3(1024), 0, stream>>>(
        lat, lat_lo, emb_hi, emb_lo, e_norm, pmin, pidxgap);

    vq_select<<<dim3(N_ROWS / 256), dim3(256), 0, stream>>>(pmin, pidxgap,
                                                            fidx, out_inds,
                                                            flagcnt, flaglist);

    vq_fixrow<<<dim3(512), dim3(FIXT), 0, stream>>>(lat, emb, flagcnt, flaglist,
                                                    fidx, out_inds);

    vq_gather<<<dim3(N_ROWS / 4), dim3(256), 0, stream>>>(lat, emb, fidx, out_q, rowpart, hist);

    vq_finalize<<<dim3(1), dim3(256), 0, stream>>>(rowpart, hist, out_loss, out_perp);

    hipMemcpyAsync(out_emb, emb, (size_t)K_CODES * D_DIM * sizeof(float),
                   hipMemcpyDeviceToDevice, stream);
}